// Round 1
// baseline (381.786 us; speedup 1.0000x reference)
//
#include <hip/hip_runtime.h>
#include <stdint.h>

// Problem constants (fixed by reference setup_inputs)
constexpr int N    = 8192;
constexpr int D    = 512;
constexpr int KEXT = 8;
constexpr int NCLS = 1000;
#define TAU_INV 14.285714285714285714f   // 1/0.07

constexpr int BM = 128, BN = 128, BK = 32;

typedef _Float16 half8 __attribute__((ext_vector_type(8)));
typedef _Float16 half4 __attribute__((ext_vector_type(4)));
typedef float    f32x4 __attribute__((ext_vector_type(4)));

typedef __attribute__((address_space(1))) void gvoid;
typedef __attribute__((address_space(3))) void lvoid;

// ---------------- small prep kernels ----------------

__global__ void zero_k(float* pos, float* neg, int* counts) {
    int i = blockIdx.x * blockDim.x + threadIdx.x;
    if (i < N)    { pos[i] = 0.f; neg[i] = 0.f; }
    if (i < NCLS) counts[i] = 0;
}

__global__ void bincount_k(const int* __restrict__ y, int* counts) {
    int i = blockIdx.x * blockDim.x + threadIdx.x;
    if (i < N) atomicAdd(&counts[y[i]], 1);
}

__global__ void inv_k(const int* __restrict__ counts, float* __restrict__ invc) {
    int i = blockIdx.x * blockDim.x + threadIdx.x;
    if (i < NCLS) invc[i] = 1.0f / (float)counts[i];   // classes with count 0 are never indexed
}

// f32 -> f16 convert of q (N*D elems), vectorized x4
__global__ void cvt_k(const float* __restrict__ q, _Float16* __restrict__ qh) {
    int i = blockIdx.x * blockDim.x + threadIdx.x;   // over N*D/4
    float4 v = reinterpret_cast<const float4*>(q)[i];
    half4 o;
    o.x = (_Float16)v.x; o.y = (_Float16)v.y; o.z = (_Float16)v.z; o.w = (_Float16)v.w;
    reinterpret_cast<half4*>(qh)[i] = o;
}

// ---------------- fused GEMM (q @ q^T) + contrastive epilogue ----------------
// m97 structure: 128x128 tile, BK=32, 4 waves in 2x2, each wave 64x64 via
// 4x4 grid of 16x16x32 f16 MFMAs. global_load_lds width=16 staging.
__global__ __launch_bounds__(256) void gemm_k(
        const _Float16* __restrict__ qh,
        const int* __restrict__ y,
        const float* __restrict__ invc,
        float* __restrict__ pos_sum,
        float* __restrict__ neg_sum) {
    __shared__ _Float16 As[BM * BK];     // row-major, 64B rows
    __shared__ _Float16 Bs[BN * BK];
    __shared__ int   yis[BM];
    __shared__ int   yjs[BN];
    __shared__ float ics[BN];

    const int tid  = threadIdx.x;
    const int wave = tid >> 6;
    const int lane = tid & 63;
    const int quad = lane >> 4;
    const int l15  = lane & 15;

    const int bi = blockIdx.y, bj = blockIdx.x;
    const int ibase = bi * BM, jbase = bj * BN;

    if (tid < BM) {
        int yj = y[jbase + tid];
        yis[tid] = y[ibase + tid];
        yjs[tid] = yj;
        ics[tid] = invc[yj];
    }

    // wave position within the 128x128 tile (2x2 waves of 64x64)
    const int wr = (wave >> 1) * 64;
    const int wc = (wave & 1) * 64;

    f32x4 acc[4][4];
#pragma unroll
    for (int a = 0; a < 4; a++)
#pragma unroll
        for (int b = 0; b < 4; b++) acc[a][b] = (f32x4)0.0f;

    // staging: wave w loads tile rows [w*32, w*32+32), 2 calls x 16 rows x 1KB
    const int srow = wave * 32 + (lane >> 2);
    const int scol = (lane & 3) * 8;
    const _Float16* gA = qh + (size_t)(ibase + srow) * D + scol;
    const _Float16* gB = qh + (size_t)(jbase + srow) * D + scol;
    char* ldsA = (char*)As + wave * 2048;
    char* ldsB = (char*)Bs + wave * 2048;

    for (int k0 = 0; k0 < D; k0 += BK) {
        __syncthreads();   // prior iter's ds_reads done before overwrite
        __builtin_amdgcn_global_load_lds((gvoid*)(gA + k0),          (lvoid*)(ldsA),        16, 0, 0);
        __builtin_amdgcn_global_load_lds((gvoid*)(gA + 16 * D + k0), (lvoid*)(ldsA + 1024), 16, 0, 0);
        __builtin_amdgcn_global_load_lds((gvoid*)(gB + k0),          (lvoid*)(ldsB),        16, 0, 0);
        __builtin_amdgcn_global_load_lds((gvoid*)(gB + 16 * D + k0), (lvoid*)(ldsB + 1024), 16, 0, 0);
        __syncthreads();   // implicit s_waitcnt vmcnt(0) drains the LDS-DMA

        half8 af[4], bfr[4];
#pragma unroll
        for (int mi = 0; mi < 4; mi++)
            af[mi] = *reinterpret_cast<const half8*>((const char*)As + (wr + mi * 16 + l15) * 64 + quad * 16);
#pragma unroll
        for (int mj = 0; mj < 4; mj++)
            bfr[mj] = *reinterpret_cast<const half8*>((const char*)Bs + (wc + mj * 16 + l15) * 64 + quad * 16);
#pragma unroll
        for (int mi = 0; mi < 4; mi++)
#pragma unroll
            for (int mj = 0; mj < 4; mj++)
                acc[mi][mj] = __builtin_amdgcn_mfma_f32_16x16x32_f16(af[mi], bfr[mj], acc[mi][mj], 0, 0, 0);
    }

    // ---- epilogue: masked exp + per-row reduction ----
    int   yj[4];
    float ic[4];
#pragma unroll
    for (int mj = 0; mj < 4; mj++) {
        int jl = wc + mj * 16 + l15;
        yj[mj] = yjs[jl];
        ic[mj] = ics[jl];
    }

#pragma unroll
    for (int mi = 0; mi < 4; mi++) {
#pragma unroll
        for (int r = 0; r < 4; r++) {
            const int il   = wr + mi * 16 + quad * 4 + r;   // C/D: row = quad*4+reg
            const int irow = ibase + il;
            const int yi   = yis[il];
            float posp = 0.f, negp = 0.f;
#pragma unroll
            for (int mj = 0; mj < 4; mj++) {
                const int jcol = jbase + wc + mj * 16 + l15; // C/D: col = lane&15
                float sim = acc[mi][mj][r] * TAU_INV;
                float e   = __expf(sim);
                bool  nz  = (sim != 0.0f);                   // faithful masked_fill(x==0,-inf)
                bool  same = (yi == yj[mj]);
                posp += (same && (irow != jcol) && nz) ? e : 0.0f;
                negp += (!same && nz) ? e * ic[mj] : 0.0f;
            }
#pragma unroll
            for (int off = 1; off < 16; off <<= 1) {         // reduce over the 16 cols in this quad
                posp += __shfl_xor(posp, off);
                negp += __shfl_xor(negp, off);
            }
            if (l15 == 0) {
                atomicAdd(&pos_sum[irow], posp);
                atomicAdd(&neg_sum[irow], negp);
            }
        }
    }
}

// ---------------- per-row finalize: k_sims (fp32) + log ratio ----------------
__global__ void finalize_k(const float* __restrict__ q, const float* __restrict__ kmat,
                           const int* __restrict__ y, const int* __restrict__ counts,
                           const float* __restrict__ pos_sum, const float* __restrict__ neg_sum,
                           float* __restrict__ loss) {
    const int wave = threadIdx.x >> 6, lane = threadIdx.x & 63;
    const int i = blockIdx.x * 4 + wave;

    float qv[8];
#pragma unroll
    for (int t = 0; t < 8; t++) qv[t] = q[(size_t)i * D + t * 64 + lane];

    float esum = 0.f;
    for (int kk = 0; kk < KEXT; kk++) {
        const float* kr = kmat + ((size_t)i * KEXT + kk) * D;
        float p = 0.f;
#pragma unroll
        for (int t = 0; t < 8; t++) p = fmaf(qv[t], kr[t * 64 + lane], p);
#pragma unroll
        for (int off = 1; off < 64; off <<= 1) p += __shfl_xor(p, off);
        esum += __expf(p * TAU_INV);
    }
    if (lane == 0) {
        float num = logf(esum + pos_sum[i]);
        float den = logf(neg_sum[i]);
        float cnt = (float)(counts[y[i]] - 1 + KEXT);  // same_class_counts, label-only
        loss[i] = -(num - den) / cnt;
    }
}

__global__ void reduce_k(const float* __restrict__ loss, float* __restrict__ out) {
    __shared__ float part[16];
    int tid = threadIdx.x;   // 1024 threads
    float s = 0.f;
    for (int i = tid; i < N; i += 1024) s += loss[i];
#pragma unroll
    for (int off = 1; off < 64; off <<= 1) s += __shfl_xor(s, off);
    if ((tid & 63) == 0) part[tid >> 6] = s;
    __syncthreads();
    if (tid < 16) {
        float v = part[tid];
#pragma unroll
        for (int off = 1; off < 16; off <<= 1) v += __shfl_xor(v, off);
        if (tid == 0) out[0] = v / (float)N;
    }
}

// ---------------- launch ----------------
extern "C" void kernel_launch(void* const* d_in, const int* in_sizes, int n_in,
                              void* d_out, int out_size, void* d_ws, size_t ws_size,
                              hipStream_t stream) {
    const float* q    = (const float*)d_in[0];
    const float* kmat = (const float*)d_in[1];
    const int*   y    = (const int*)d_in[2];
    float* out = (float*)d_out;

    char* ws = (char*)d_ws;
    _Float16* qh   = (_Float16*)ws;                 // 8 MB: N*D f16
    int*   counts  = (int*)  (ws + 8388608);        // 1000 ints
    float* invc    = (float*)(ws + 8392608);        // 1000 floats
    float* pos     = (float*)(ws + 8396608);        // N floats
    float* neg     = (float*)(ws + 8429376);        // N floats
    float* loss    = (float*)(ws + 8462144);        // N floats

    zero_k    <<<32, 256, 0, stream>>>(pos, neg, counts);
    bincount_k<<<32, 256, 0, stream>>>(y, counts);
    inv_k     <<<4, 256, 0, stream>>>(counts, invc);
    cvt_k     <<<(N * D / 4) / 256, 256, 0, stream>>>(q, qh);
    dim3 g(N / BN, N / BM);
    gemm_k    <<<g, 256, 0, stream>>>(qh, y, invc, pos, neg);
    finalize_k<<<N / 4, 256, 0, stream>>>(q, kmat, y, counts, pos, neg, loss);
    reduce_k  <<<1, 1024, 0, stream>>>(loss, out);
}